// Round 8
// baseline (831.912 us; speedup 1.0000x reference)
//
#include <hip/hip_runtime.h>
#include <math.h>

#define NBATCH 512
#define NDIM 256
#define NHID 512
#define NC 32
#define NTAIL 30
#define NP 64
#define TEV 16
#define MAXIT 10
#define TOLF 0.01f
#define PI_F 3.14159265358979323846f

typedef __bf16 bf16_t;
typedef __bf16 bf16x8 __attribute__((ext_vector_type(8)));
typedef float f32x4 __attribute__((ext_vector_type(4)));
typedef unsigned short ushort_t;

// ---- workspace layout (float slots) ----
constexpr size_t OFF_TCHEB = 0;        // 64
constexpr size_t OFF_PHIT  = 64;       // 2048
constexpr size_t OFF_PD2I  = 2112;     // 64
constexpr size_t OFF_M2    = 2176;     // 64
constexpr size_t OFF_INV0  = 2240;     // 16
constexpr size_t OFF_PHIOUT= 2256;     // 512
constexpr size_t OFF_PQ    = 2768;     // 2048 (setup scratch)
constexpr size_t OFF_PQBH  = 4816;     // [32][64] bf16 hi (1024 floats)
constexpr size_t OFF_PQBL  = 5840;     // 1024
constexpr size_t OFF_PHIH  = 6864;     // [64][32] bf16 hi of Phi (A-layout), 1024 floats
constexpr size_t OFF_PHIL  = 7888;     // 1024
constexpr size_t OFF_SCAL  = 8912;     // accum double [0:1], done [2], counter [3]
constexpr size_t OFF_H1F   = 8928;
constexpr size_t OFF_YF2I  = OFF_H1F + 262144;
constexpr size_t OFF_YM2   = OFF_YF2I + 262144;
constexpr size_t OFF_BT    = OFF_YM2 + 3932160;
constexpr size_t OFF_W1T   = OFF_BT + 3932160;    // [512][256] bf16
constexpr size_t OFF_W2T   = OFF_W1T + 65536;     // [256][512] bf16
constexpr size_t WS_FLOATS = OFF_W2T + 65536;

// ---- output layout (floats) ----
constexpr size_t OUT_TEVAL = 0;
constexpr size_t OUT_TRAJ  = 16;
constexpr size_t OUT_DELTA = 16 + (size_t)TEV*NBATCH*NDIM;
constexpr size_t OUT_B     = OUT_DELTA + 1;

__device__ __forceinline__ ushort_t bf16bits(float v) {
    bf16_t h = (bf16_t)v; ushort_t u; __builtin_memcpy(&u, &h, 2); return u;
}
__device__ __forceinline__ float bf16val(ushort_t u) {
    bf16_t h; __builtin_memcpy(&h, &u, 2); return (float)h;
}

// ============ setup: spectral operators (round-2/6 proven fp64 parallel GJ) ============
__global__ void setup_kernel(const float* __restrict__ t_eval, float* __restrict__ ws,
                             float* __restrict__ out)
{
    __shared__ float Phi[32][64];
    __shared__ float DPhi[32][64];
    __shared__ float Phib[30][64];
    __shared__ float tcs[64];
    __shared__ float DtS[64];
    __shared__ float inv0s[4];
    __shared__ float pd2s[30][2];
    __shared__ double Gaug[30][61];
    __shared__ double rowk[60];
    __shared__ double colk[30];

    const int tid = threadIdx.x;
    const float t0 = t_eval[0], t1 = t_eval[TEV-1];
    const float sgn = (t1 > t0) ? 1.f : -1.f;

    if (tid < 64) {
        const float t = -sgn * cosf(PI_F * (float)tid / 64.f);
        tcs[tid] = t;
        float p0 = 1.f, p1 = t;
        Phi[0][tid] = p0; Phi[1][tid] = p1;
        for (int k = 2; k < 32; ++k) { float pk = 2.f*t*p1 - p0; Phi[k][tid] = pk; p0 = p1; p1 = pk; }
        const float sc = 2.f / (t1 - t0);
        float u0 = 1.f, u1 = 2.f*t;
        DPhi[0][tid] = 0.f;
        DPhi[1][tid] = sc * 1.f * u0;
        DPhi[2][tid] = sc * 2.f * u1;
        for (int k = 3; k < 32; ++k) { float uk = 2.f*t*u1 - u0; DPhi[k][tid] = sc * (float)k * uk; u0 = u1; u1 = uk; }
    }
    __syncthreads();
    if (tid < 64) DtS[tid] = ((tid < 63) ? tcs[tid+1] : 1.0f) - tcs[tid];
    if (tid == 0) {
        double a = Phi[0][0], b = DPhi[0][0], c = Phi[1][0], d = DPhi[1][0];
        double det = a*d - b*c;
        inv0s[0] = (float)( d/det); inv0s[1] = (float)(-b/det);
        inv0s[2] = (float)(-c/det); inv0s[3] = (float)( a/det);
    }
    __syncthreads();
    if (tid == 0) { ws[OFF_INV0+0]=inv0s[0]; ws[OFF_INV0+1]=inv0s[1]; ws[OFF_INV0+2]=inv0s[2]; ws[OFF_INV0+3]=inv0s[3]; }
    if (tid < 30) {
        float P = Phi[2+tid][0], D = DPhi[2+tid][0];
        float a0 = P*inv0s[0] + D*inv0s[2];
        float a1 = P*inv0s[1] + D*inv0s[3];
        pd2s[tid][0] = a0; pd2s[tid][1] = a1;
        ws[OFF_PD2I + tid*2+0] = a0;
        ws[OFF_PD2I + tid*2+1] = a1;
    }
    __syncthreads();
    if (tid < 64)
        for (int m = 0; m < 30; ++m)
            Phib[m][tid] = DPhi[2+m][tid] - (pd2s[m][0]*DPhi[0][tid] + pd2s[m][1]*DPhi[1][tid]);
    __syncthreads();

    for (int e = tid; e < 900; e += 256) {
        int i = e / 30, j = e % 30;
        double s = 0.0;
        for (int p = 0; p < 64; ++p) s += (double)Phib[i][p] * (double)DtS[p] * (double)Phib[j][p];
        Gaug[i][j] = s;
        Gaug[i][30+j] = (i == j) ? 1.0 : 0.0;
    }
    __syncthreads();

    for (int k = 0; k < 30; ++k) {
        double invpv = 1.0 / Gaug[k][k];
        if (tid < 60) rowk[tid] = Gaug[k][tid] * invpv;
        if (tid >= 64 && tid < 94) colk[tid-64] = Gaug[tid-64][k];
        __syncthreads();
        for (int e = tid; e < 1800; e += 256) {
            int i = e / 60, j = e - i*60;
            if (i == k) Gaug[i][j] = rowk[j];
            else        Gaug[i][j] -= colk[i] * rowk[j];
        }
        __syncthreads();
    }

    if (tid < 64) {
        ushort_t* pqh = (ushort_t*)(ws + OFF_PQBH);
        ushort_t* pql = (ushort_t*)(ws + OFF_PQBL);
        float pqrow[32];
        for (int n = 0; n < 30; ++n) {
            double s = 0.0;
            for (int m = 0; m < 30; ++m) s += (double)Phib[m][tid] * Gaug[m][30+n];
            pqrow[n] = (float)((double)DtS[tid] * s);
        }
        pqrow[30] = 0.f; pqrow[31] = 0.f;
        for (int n = 0; n < 32; ++n) {
            ws[OFF_PQ + (size_t)tid*32 + n] = pqrow[n];
            bf16_t h = (bf16_t)pqrow[n];
            float hf = (float)h;
            pqh[n*64 + tid] = bf16bits(pqrow[n]);
            pql[n*64 + tid] = bf16bits(pqrow[n] - hf);
        }
    }
    __syncthreads();

    if (tid < 30) {
        double a20 = 0.0, a21 = 0.0;
        for (int p = 0; p < 64; ++p) {
            double pq = (double)ws[OFF_PQ + (size_t)p*32 + tid];
            a20 += (double)DPhi[0][p] * pq;
            a21 += (double)DPhi[1][p] * pq;
        }
        ws[OFF_M2 + 0*32 + tid] = (float)((double)inv0s[0]*a20 + (double)inv0s[1]*a21);
        ws[OFF_M2 + 1*32 + tid] = (float)((double)inv0s[2]*a20 + (double)inv0s[3]*a21);
    }

    if (tid < 64) {
        ushort_t* phh = (ushort_t*)(ws + OFF_PHIH);
        ushort_t* phl = (ushort_t*)(ws + OFF_PHIL);
        for (int n = 0; n < 32; ++n) {
            float f = Phi[n][tid];
            ws[OFF_PHIT + (size_t)tid*32 + n] = f;
            ushort_t hb = bf16bits(f);
            phh[tid*32 + n] = hb;
            phl[tid*32 + n] = bf16bits(f - bf16val(hb));
        }
        ws[OFF_TCHEB + tid] = tcs[tid];
    }

    if (tid < TEV) {
        float te = t_eval[tid];
        out[OUT_TEVAL + tid] = te;
        float tt = -1.f + 2.f*(te - t0)/(t1 - t0);
        float q0 = 1.f, q1 = tt;
        ws[OFF_PHIOUT + (size_t)tid*32 + 0] = q0;
        ws[OFF_PHIOUT + (size_t)tid*32 + 1] = q1;
        for (int k = 2; k < 32; ++k) { float qk = 2.f*tt*q1 - q0; ws[OFF_PHIOUT + (size_t)tid*32 + k] = qk; q0 = q1; q1 = qk; }
    }

    if (tid == 0) {
        double* acc = (double*)(ws + OFF_SCAL);
        acc[0] = 0.0;
        int* ip = (int*)(ws + OFF_SCAL + 2);
        ip[0] = 0;  // done
        ip[1] = 0;  // counter
    }
}

// ============ B_init [b][d][n] -> Bt [b][n][d] ============
__global__ __launch_bounds__(256) void transB_kernel(const float* __restrict__ Bin, float* __restrict__ Bt)
{
    const int t = threadIdx.x, b = blockIdx.x;
    const float* src = Bin + ((size_t)(b*NDIM + t)) * NTAIL;
    #pragma unroll
    for (int n = 0; n < NTAIL; ++n)
        Bt[((size_t)b*NTAIL + n)*NDIM + t] = src[n];
}

// ============ W [R][C] f32 -> Wt [C][R] bf16 ============
__global__ __launch_bounds__(256) void transW_kernel(const float* __restrict__ W, bf16_t* __restrict__ Wt,
                                                     int R, int C)
{
    __shared__ float Ls[64][65];
    const int r0 = blockIdx.x*64, c0 = blockIdx.y*64;
    const int lr = threadIdx.x >> 6, lc = threadIdx.x & 63;
    #pragma unroll
    for (int i = 0; i < 16; ++i) {
        int rr = i*4 + lr;
        Ls[rr][lc] = W[(size_t)(r0+rr)*C + c0+lc];
    }
    __syncthreads();
    #pragma unroll
    for (int i = 0; i < 16; ++i) {
        int cc = i*4 + lr;
        Wt[(size_t)(c0+cc)*R + r0 + lc] = (bf16_t)Ls[lc][cc];
    }
}

// ============ f_init ============
__global__ __launch_bounds__(512) void finit_h_kernel(const float* __restrict__ y, const float* __restrict__ W1,
                                                      const float* __restrict__ b1, const float* __restrict__ t_eval,
                                                      float* __restrict__ h1)
{
    __shared__ float ys[NDIM];
    const int t = threadIdx.x, b = blockIdx.x;
    if (t < NDIM) ys[t] = y[(size_t)b*NDIM + t];
    __syncthreads();
    float acc = b1[t] + t_eval[0];
    for (int d = 0; d < NDIM; ++d) acc += ys[d] * W1[(size_t)d*NHID + t];
    h1[(size_t)b*NHID + t] = tanhf(acc);
}

__global__ __launch_bounds__(256) void finit_rest_kernel(const float* __restrict__ y, const float* __restrict__ W2,
                                                         const float* __restrict__ b2, const float* __restrict__ h1,
                                                         const float* __restrict__ inv0, const float* __restrict__ M2,
                                                         float* __restrict__ yf2i, float* __restrict__ yM2)
{
    __shared__ float hs[NHID];
    const int t = threadIdx.x, b = blockIdx.x;
    hs[t] = h1[(size_t)b*NHID + t];
    hs[t+256] = h1[(size_t)b*NHID + 256 + t];
    __syncthreads();
    float f = b2[t];
    for (int h = 0; h < NHID; ++h) f += hs[h] * W2[(size_t)h*NDIM + t];
    const float yv = y[(size_t)b*NDIM + t];
    yf2i[((size_t)b*2 + 0)*NDIM + t] = yv*inv0[0] + f*inv0[2];
    yf2i[((size_t)b*2 + 1)*NDIM + t] = yv*inv0[1] + f*inv0[3];
    #pragma unroll
    for (int n = 0; n < NTAIL; ++n)
        yM2[((size_t)b*NTAIL + n)*NDIM + t] = yv*M2[n] + f*M2[32 + n];
}

// ============ fused iteration kernel: 512 blocks (1 batch each) x 256 threads, 3 blocks/CU ============
__global__ __launch_bounds__(256, 3) void iter_kernel(
    const float* __restrict__ pd2i, const float* __restrict__ yf2i, const float* __restrict__ tch,
    const bf16_t* __restrict__ W1t, const bf16_t* __restrict__ W2t,
    const float* __restrict__ b1f, const float* __restrict__ b2f,
    const ushort_t* __restrict__ PQhi, const ushort_t* __restrict__ PQlo,
    const ushort_t* __restrict__ phiH, const ushort_t* __restrict__ phiL,
    const float* __restrict__ yM2, float* __restrict__ Bt,
    double* __restrict__ accum, int* __restrict__ counter,
    int* __restrict__ done, float* __restrict__ outDelta)
{
    if (*done) return;
    __shared__ float pd2s[32][2];
    __shared__ float tchS[64];
    __shared__ double redd[4];
    __shared__ __align__(16) char smemA[33792];  // BfT hi/lo -> Ay [64][264]us -> FsT [256][33]u32
    __shared__ __align__(16) char smemB[17408];  // Hc [64][136]us

    const int t = threadIdx.x;
    const int b = blockIdx.x;            // batch index 0..511
    const int lane = t & 63, w = t >> 6;
    const int fr = lane & 15, quad = lane >> 4;

    // ---- constants ----
    if (t < 60) ((float*)pd2s)[t] = pd2i[t];
    if (t >= 64 && t < 128) tchS[t-64] = tch[t-64];

    // ---- stage 0a: head coefficients per thread (t = d), write BfT hi/lo [256 d][32 n] swizzled ----
    {
        float cf[32];
        #pragma unroll
        for (int n = 0; n < NTAIL; ++n) cf[2+n] = Bt[((size_t)b*NTAIL + n)*NDIM + t];
        float c0 = yf2i[((size_t)b*2 + 0)*NDIM + t];
        float c1 = yf2i[((size_t)b*2 + 1)*NDIM + t];
        #pragma unroll
        for (int n = 0; n < NTAIL; ++n) { c0 -= cf[2+n]*pd2s[n][0]; c1 -= cf[2+n]*pd2s[n][1]; }
        cf[0] = c0; cf[1] = c1;
        unsigned* BH32 = (unsigned*)smemA;             // [256][16] u32 (block-swizzled)
        unsigned* BL32 = (unsigned*)(smemA + 16384);
        #pragma unroll
        for (int n2 = 0; n2 < 16; ++n2) {
            float f0 = cf[2*n2], f1 = cf[2*n2+1];
            ushort_t h0 = bf16bits(f0), h1 = bf16bits(f1);
            ushort_t l0 = bf16bits(f0 - bf16val(h0)), l1 = bf16bits(f1 - bf16val(h1));
            int idx = t*16 + ((n2 >> 2) ^ (t & 3))*4 + (n2 & 3);
            BH32[idx] = (unsigned)h0 | ((unsigned)h1 << 16);
            BL32[idx] = (unsigned)l0 | ((unsigned)l1 << 16);
        }
    }
    __syncthreads();

    // ---- stage 0b: y = Phi @ Bfull via MFMA (hi/lo 3-product), write Ay [64 p][264] bf16 ----
    ushort_t* Ay = (ushort_t*)smemA;
    {
        bf16x8 bH[4], bL[4];
        const ushort_t* BHu = (const ushort_t*)smemA;
        const ushort_t* BLu = (const ushort_t*)(smemA + 16384);
        #pragma unroll
        for (int j = 0; j < 4; ++j) {
            const int d = w*64 + j*16 + fr;
            const int off = d*32 + (quad ^ (d & 3))*8;
            bH[j] = *(const bf16x8*)(BHu + off);
            bL[j] = *(const bf16x8*)(BLu + off);
        }
        bf16x8 aH[4], aL[4];
        #pragma unroll
        for (int i = 0; i < 4; ++i) {
            aH[i] = *(const bf16x8*)(phiH + (i*16 + fr)*32 + quad*8);
            aL[i] = *(const bf16x8*)(phiL + (i*16 + fr)*32 + quad*8);
        }
        __syncthreads();   // all BfT reads done before Ay overwrite
        f32x4 accY[4][4];
        #pragma unroll
        for (int i = 0; i < 4; ++i)
            #pragma unroll
            for (int j = 0; j < 4; ++j) {
                f32x4 a = (f32x4){0.f,0.f,0.f,0.f};
                a = __builtin_amdgcn_mfma_f32_16x16x32_bf16(aH[i], bH[j], a, 0, 0, 0);
                a = __builtin_amdgcn_mfma_f32_16x16x32_bf16(aH[i], bL[j], a, 0, 0, 0);
                a = __builtin_amdgcn_mfma_f32_16x16x32_bf16(aL[i], bH[j], a, 0, 0, 0);
                accY[i][j] = a;
            }
        #pragma unroll
        for (int i = 0; i < 4; ++i)
            #pragma unroll
            for (int j = 0; j < 4; ++j)
                #pragma unroll
                for (int r = 0; r < 4; ++r) {
                    const int p = i*16 + quad*4 + r;
                    const int d = w*64 + j*16 + fr;
                    Ay[p*264 + d] = bf16bits(accY[i][j][r]);
                }
    }
    __syncthreads();

    // ---- GEMM1 + tanh + GEMM2 over 4 nh-passes of 128 ----
    ushort_t* Hc = (ushort_t*)smemB;     // [64][136]
    f32x4 accF[4][4];                    // rows i*16, d-cols w*64 + j*16
    #pragma unroll
    for (int i = 0; i < 4; ++i)
        #pragma unroll
        for (int j = 0; j < 4; ++j) accF[i][j] = (f32x4){0.f,0.f,0.f,0.f};

    #pragma unroll
    for (int pass = 0; pass < 4; ++pass) {
        // GEMM1: acc1 = y(64x256) @ W1 chunk (256 x 128)
        f32x4 acc1[4][2];
        #pragma unroll
        for (int i = 0; i < 4; ++i)
            #pragma unroll
            for (int j = 0; j < 2; ++j) acc1[i][j] = (f32x4){0.f,0.f,0.f,0.f};
        #pragma unroll 4
        for (int kt = 0; kt < NDIM; kt += 32) {
            bf16x8 af[4], bfj[2];
            #pragma unroll
            for (int i = 0; i < 4; ++i)
                af[i] = *(const bf16x8*)(Ay + (i*16 + fr)*264 + kt + quad*8);
            #pragma unroll
            for (int j = 0; j < 2; ++j) {
                const int ncol = pass*128 + w*32 + j*16 + fr;
                bfj[j] = *(const bf16x8*)(W1t + (size_t)ncol*NDIM + kt + quad*8);
            }
            #pragma unroll
            for (int i = 0; i < 4; ++i)
                #pragma unroll
                for (int j = 0; j < 2; ++j)
                    acc1[i][j] = __builtin_amdgcn_mfma_f32_16x16x32_bf16(af[i], bfj[j], acc1[i][j], 0, 0, 0);
        }
        __syncthreads();   // prev pass GEMM2 Hc reads done
        #pragma unroll
        for (int i = 0; i < 4; ++i)
            #pragma unroll
            for (int j = 0; j < 2; ++j) {
                const int col = w*32 + j*16 + fr;
                const float bv = b1f[pass*128 + col];
                #pragma unroll
                for (int r = 0; r < 4; ++r) {
                    const int row = i*16 + quad*4 + r;   // = p, 0..63
                    float v = acc1[i][j][r] + bv + tchS[row];
                    v = fminf(fmaxf(v, -15.f), 15.f);
                    float e = __expf(2.f*v);
                    Hc[row*136 + col] = bf16bits((e - 1.f)/(e + 1.f));
                }
            }
        __syncthreads();
        // GEMM2 partial: accF += Hc(64x128) @ W2 chunk (128 x 256)
        #pragma unroll
        for (int kt = 0; kt < 128; kt += 32) {
            bf16x8 af[4], bfj[4];
            #pragma unroll
            for (int i = 0; i < 4; ++i)
                af[i] = *(const bf16x8*)(Hc + (i*16 + fr)*136 + kt + quad*8);
            #pragma unroll
            for (int j = 0; j < 4; ++j) {
                const int d = w*64 + j*16 + fr;
                bfj[j] = *(const bf16x8*)(W2t + (size_t)d*NHID + pass*128 + kt + quad*8);
            }
            #pragma unroll
            for (int i = 0; i < 4; ++i)
                #pragma unroll
                for (int j = 0; j < 4; ++j)
                    accF[i][j] = __builtin_amdgcn_mfma_f32_16x16x32_bf16(af[i], bfj[j], accF[i][j], 0, 0, 0);
        }
    }
    __syncthreads();   // last GEMM1's Ay reads done; smemA reusable

    // ---- F (+b2) -> FsT [256 d][33] u32 (bf16 row-pairs) ----
    {
        unsigned* FsT32 = (unsigned*)smemA;
        #pragma unroll
        for (int i = 0; i < 4; ++i)
            #pragma unroll
            for (int j = 0; j < 4; ++j) {
                const int d = w*64 + j*16 + fr;
                const float bv = b2f[d];
                #pragma unroll
                for (int rp = 0; rp < 2; ++rp) {
                    unsigned u0 = bf16bits(accF[i][j][rp*2]   + bv);
                    unsigned u1 = bf16bits(accF[i][j][rp*2+1] + bv);
                    FsT32[d*33 + i*8 + quad*2 + rp] = u0 | (u1 << 16);
                }
            }
    }
    __syncthreads();

    // ---- PQ contraction: B_new[n][d] = sum_p PQ[n][p]*F[p][d] - yM2, update Bt + norm ----
    double ss = 0.0;
    {
        const ushort_t* FsTu = (const ushort_t*)smemA;
        f32x4 acc2[2][4];
        #pragma unroll
        for (int m2 = 0; m2 < 2; ++m2)
            #pragma unroll
            for (int j2 = 0; j2 < 4; ++j2) acc2[m2][j2] = (f32x4){0.f,0.f,0.f,0.f};
        #pragma unroll
        for (int kk = 0; kk < 2; ++kk) {
            bf16x8 ah[2], al[2];
            #pragma unroll
            for (int m2 = 0; m2 < 2; ++m2) {
                const int off = (m2*16 + fr)*64 + kk*32 + quad*8;   // PQ [n][p] direct from L2
                ah[m2] = *(const bf16x8*)(PQhi + off);
                al[m2] = *(const bf16x8*)(PQlo + off);
            }
            #pragma unroll
            for (int j2 = 0; j2 < 4; ++j2) {
                const int d2 = w*64 + j2*16 + fr;
                bf16x8 bfv = *(const bf16x8*)(FsTu + d2*66 + kk*32 + quad*8);
                #pragma unroll
                for (int m2 = 0; m2 < 2; ++m2) {
                    acc2[m2][j2] = __builtin_amdgcn_mfma_f32_16x16x32_bf16(ah[m2], bfv, acc2[m2][j2], 0, 0, 0);
                    acc2[m2][j2] = __builtin_amdgcn_mfma_f32_16x16x32_bf16(al[m2], bfv, acc2[m2][j2], 0, 0, 0);
                }
            }
        }
        #pragma unroll
        for (int m2 = 0; m2 < 2; ++m2)
            #pragma unroll
            for (int j2 = 0; j2 < 4; ++j2)
                #pragma unroll
                for (int rr = 0; rr < 4; ++rr) {
                    const int n = m2*16 + quad*4 + rr;
                    if (n < NTAIL) {
                        const int d = w*64 + j2*16 + fr;
                        const size_t idx = ((size_t)b*NTAIL + n)*NDIM + d;
                        float val = acc2[m2][j2][rr] - yM2[idx];
                        float old = Bt[idx];
                        float diff = val - old;
                        Bt[idx] = val;
                        ss += (double)diff*(double)diff;
                    }
                }
    }

    #pragma unroll
    for (int off = 32; off > 0; off >>= 1) ss += __shfl_down(ss, off, 64);
    if (lane == 0) redd[w] = ss;
    __syncthreads();
    if (t == 0) {
        double tot = redd[0] + redd[1] + redd[2] + redd[3];
        atomicAdd(accum, tot);
        __threadfence();
        int old = atomicAdd(counter, 1);
        if (old == 511) {   // last of 512 blocks
            unsigned long long raw = atomicExch((unsigned long long*)accum, 0ull);
            double total; __builtin_memcpy(&total, &raw, 8);
            float dl = (float)sqrt(total);
            *outDelta = dl;
            *counter = 0;
            if (dl < TOLF) *done = 1;
        }
    }
}

// ============ epilogue: traj + B output ============
__global__ __launch_bounds__(256) void kernelEpi(const float* __restrict__ PhiOut, const float* __restrict__ pd2i,
                                                 const float* __restrict__ yf2i, const float* __restrict__ Bt,
                                                 float* __restrict__ outTraj, float* __restrict__ outB)
{
    __shared__ float Po[16][32];
    const int t = threadIdx.x, b = blockIdx.x;
    for (int i = t; i < 512; i += 256) ((float*)Po)[i] = PhiOut[i];
    __syncthreads();
    float cf[32];
    #pragma unroll
    for (int n = 0; n < NTAIL; ++n) cf[2+n] = Bt[((size_t)b*NTAIL + n)*NDIM + t];
    float c0 = yf2i[((size_t)b*2 + 0)*NDIM + t];
    float c1 = yf2i[((size_t)b*2 + 1)*NDIM + t];
    #pragma unroll
    for (int n = 0; n < NTAIL; ++n) { c0 -= cf[2+n]*pd2i[n*2]; c1 -= cf[2+n]*pd2i[n*2+1]; }
    cf[0] = c0; cf[1] = c1;
    for (int tt = 0; tt < TEV; ++tt) {
        float s = 0.f;
        #pragma unroll
        for (int k = 0; k < 32; ++k) s += cf[k]*Po[tt][k];
        outTraj[((size_t)tt*NBATCH + b)*NDIM + t] = s;
    }
    float* ob = outB + ((size_t)(b*NDIM + t))*NTAIL;
    #pragma unroll
    for (int n = 0; n < NTAIL; ++n) ob[n] = cf[2+n];
}

extern "C" void kernel_launch(void* const* d_in, const int* in_sizes, int n_in,
                              void* d_out, int out_size, void* d_ws, size_t ws_size,
                              hipStream_t stream)
{
    const float* y_init = (const float*)d_in[0];
    const float* t_eval = (const float*)d_in[1];
    const float* B_init = (const float*)d_in[2];
    const float* W1     = (const float*)d_in[3];
    const float* b1     = (const float*)d_in[4];
    const float* W2     = (const float*)d_in[5];
    const float* b2     = (const float*)d_in[6];
    float* out = (float*)d_out;
    float* ws  = (float*)d_ws;
    if (ws_size < WS_FLOATS * sizeof(float)) return;

    float* tcheb = ws + OFF_TCHEB;
    float* pd2i  = ws + OFF_PD2I;
    float* M2    = ws + OFF_M2;
    float* inv0  = ws + OFF_INV0;
    float* PhiOut= ws + OFF_PHIOUT;
    double* accum = (double*)(ws + OFF_SCAL);
    int* done    = (int*)(ws + OFF_SCAL + 2);
    int* counter = (int*)(ws + OFF_SCAL + 3);
    float* h1   = ws + OFF_H1F;
    float* yf2i = ws + OFF_YF2I;
    float* yM2  = ws + OFF_YM2;
    float* Bt   = ws + OFF_BT;
    bf16_t* W1t = (bf16_t*)(ws + OFF_W1T);
    bf16_t* W2t = (bf16_t*)(ws + OFF_W2T);
    ushort_t* pqh = (ushort_t*)(ws + OFF_PQBH);
    ushort_t* pql = (ushort_t*)(ws + OFF_PQBL);
    ushort_t* phh = (ushort_t*)(ws + OFF_PHIH);
    ushort_t* phl = (ushort_t*)(ws + OFF_PHIL);

    setup_kernel<<<1, 256, 0, stream>>>(t_eval, ws, out);
    transB_kernel<<<NBATCH, 256, 0, stream>>>(B_init, Bt);
    transW_kernel<<<dim3(NDIM/64, NHID/64), 256, 0, stream>>>(W1, W1t, NDIM, NHID);
    transW_kernel<<<dim3(NHID/64, NDIM/64), 256, 0, stream>>>(W2, W2t, NHID, NDIM);
    finit_h_kernel<<<NBATCH, 512, 0, stream>>>(y_init, W1, b1, t_eval, h1);
    finit_rest_kernel<<<NBATCH, 256, 0, stream>>>(y_init, W2, b2, h1, inv0, M2, yf2i, yM2);

    for (int it = 0; it < MAXIT; ++it) {
        iter_kernel<<<NBATCH, 256, 0, stream>>>(pd2i, yf2i, tcheb, W1t, W2t, b1, b2,
                                                pqh, pql, phh, phl, yM2, Bt,
                                                accum, counter, done, out + OUT_DELTA);
    }
    kernelEpi<<<NBATCH, 256, 0, stream>>>(PhiOut, pd2i, yf2i, Bt, out + OUT_TRAJ, out + OUT_B);
}

// Round 9
// 793.495 us; speedup vs baseline: 1.0484x; 1.0484x over previous
//
#include <hip/hip_runtime.h>
#include <math.h>

#define NBATCH 512
#define NDIM 256
#define NHID 512
#define NC 32
#define NTAIL 30
#define NP 64
#define TEV 16
#define MAXIT 10
#define TOLF 0.01f
#define PI_F 3.14159265358979323846f

typedef __bf16 bf16_t;
typedef __bf16 bf16x8 __attribute__((ext_vector_type(8)));
typedef float f32x4 __attribute__((ext_vector_type(4)));
typedef unsigned short ushort_t;

// ---- workspace layout (float slots) ----
constexpr size_t OFF_TCHEB = 0;        // 64
constexpr size_t OFF_PHIT  = 64;       // 2048
constexpr size_t OFF_PD2I  = 2112;     // 64
constexpr size_t OFF_M2    = 2176;     // 64
constexpr size_t OFF_INV0  = 2240;     // 16
constexpr size_t OFF_PHIOUT= 2256;     // 512
constexpr size_t OFF_PQ    = 2768;     // 2048 (setup scratch)
constexpr size_t OFF_PQBH  = 4816;     // [32][64] bf16 hi (1024 floats)
constexpr size_t OFF_PQBL  = 5840;     // 1024
constexpr size_t OFF_PHIH  = 6864;     // [64][32] bf16 hi of Phi (A-layout), 1024 floats
constexpr size_t OFF_PHIL  = 7888;     // 1024
constexpr size_t OFF_SCAL  = 8912;     // accum double [0:1], done [2], counter [3]
constexpr size_t OFF_H1F   = 8928;
constexpr size_t OFF_YF2I  = OFF_H1F + 262144;
constexpr size_t OFF_YM2   = OFF_YF2I + 262144;
constexpr size_t OFF_BT    = OFF_YM2 + 3932160;
constexpr size_t OFF_W1T   = OFF_BT + 3932160;    // [512][256] bf16
constexpr size_t OFF_W2T   = OFF_W1T + 65536;     // [256][512] bf16
constexpr size_t WS_FLOATS = OFF_W2T + 65536;

// ---- output layout (floats) ----
constexpr size_t OUT_TEVAL = 0;
constexpr size_t OUT_TRAJ  = 16;
constexpr size_t OUT_DELTA = 16 + (size_t)TEV*NBATCH*NDIM;
constexpr size_t OUT_B     = OUT_DELTA + 1;

__device__ __forceinline__ ushort_t bf16bits(float v) {
    bf16_t h = (bf16_t)v; ushort_t u; __builtin_memcpy(&u, &h, 2); return u;
}
__device__ __forceinline__ float bf16val(ushort_t u) {
    bf16_t h; __builtin_memcpy(&h, &u, 2); return (float)h;
}

// ============ setup: spectral operators (round-2/6 proven fp64 parallel GJ) ============
__global__ void setup_kernel(const float* __restrict__ t_eval, float* __restrict__ ws,
                             float* __restrict__ out)
{
    __shared__ float Phi[32][64];
    __shared__ float DPhi[32][64];
    __shared__ float Phib[30][64];
    __shared__ float tcs[64];
    __shared__ float DtS[64];
    __shared__ float inv0s[4];
    __shared__ float pd2s[30][2];
    __shared__ double Gaug[30][61];
    __shared__ double rowk[60];
    __shared__ double colk[30];

    const int tid = threadIdx.x;
    const float t0 = t_eval[0], t1 = t_eval[TEV-1];
    const float sgn = (t1 > t0) ? 1.f : -1.f;

    if (tid < 64) {
        const float t = -sgn * cosf(PI_F * (float)tid / 64.f);
        tcs[tid] = t;
        float p0 = 1.f, p1 = t;
        Phi[0][tid] = p0; Phi[1][tid] = p1;
        for (int k = 2; k < 32; ++k) { float pk = 2.f*t*p1 - p0; Phi[k][tid] = pk; p0 = p1; p1 = pk; }
        const float sc = 2.f / (t1 - t0);
        float u0 = 1.f, u1 = 2.f*t;
        DPhi[0][tid] = 0.f;
        DPhi[1][tid] = sc * 1.f * u0;
        DPhi[2][tid] = sc * 2.f * u1;
        for (int k = 3; k < 32; ++k) { float uk = 2.f*t*u1 - u0; DPhi[k][tid] = sc * (float)k * uk; u0 = u1; u1 = uk; }
    }
    __syncthreads();
    if (tid < 64) DtS[tid] = ((tid < 63) ? tcs[tid+1] : 1.0f) - tcs[tid];
    if (tid == 0) {
        double a = Phi[0][0], b = DPhi[0][0], c = Phi[1][0], d = DPhi[1][0];
        double det = a*d - b*c;
        inv0s[0] = (float)( d/det); inv0s[1] = (float)(-b/det);
        inv0s[2] = (float)(-c/det); inv0s[3] = (float)( a/det);
    }
    __syncthreads();
    if (tid == 0) { ws[OFF_INV0+0]=inv0s[0]; ws[OFF_INV0+1]=inv0s[1]; ws[OFF_INV0+2]=inv0s[2]; ws[OFF_INV0+3]=inv0s[3]; }
    if (tid < 30) {
        float P = Phi[2+tid][0], D = DPhi[2+tid][0];
        float a0 = P*inv0s[0] + D*inv0s[2];
        float a1 = P*inv0s[1] + D*inv0s[3];
        pd2s[tid][0] = a0; pd2s[tid][1] = a1;
        ws[OFF_PD2I + tid*2+0] = a0;
        ws[OFF_PD2I + tid*2+1] = a1;
    }
    __syncthreads();
    if (tid < 64)
        for (int m = 0; m < 30; ++m)
            Phib[m][tid] = DPhi[2+m][tid] - (pd2s[m][0]*DPhi[0][tid] + pd2s[m][1]*DPhi[1][tid]);
    __syncthreads();

    for (int e = tid; e < 900; e += 256) {
        int i = e / 30, j = e % 30;
        double s = 0.0;
        for (int p = 0; p < 64; ++p) s += (double)Phib[i][p] * (double)DtS[p] * (double)Phib[j][p];
        Gaug[i][j] = s;
        Gaug[i][30+j] = (i == j) ? 1.0 : 0.0;
    }
    __syncthreads();

    for (int k = 0; k < 30; ++k) {
        double invpv = 1.0 / Gaug[k][k];
        if (tid < 60) rowk[tid] = Gaug[k][tid] * invpv;
        if (tid >= 64 && tid < 94) colk[tid-64] = Gaug[tid-64][k];
        __syncthreads();
        for (int e = tid; e < 1800; e += 256) {
            int i = e / 60, j = e - i*60;
            if (i == k) Gaug[i][j] = rowk[j];
            else        Gaug[i][j] -= colk[i] * rowk[j];
        }
        __syncthreads();
    }

    if (tid < 64) {
        ushort_t* pqh = (ushort_t*)(ws + OFF_PQBH);
        ushort_t* pql = (ushort_t*)(ws + OFF_PQBL);
        float pqrow[32];
        for (int n = 0; n < 30; ++n) {
            double s = 0.0;
            for (int m = 0; m < 30; ++m) s += (double)Phib[m][tid] * Gaug[m][30+n];
            pqrow[n] = (float)((double)DtS[tid] * s);
        }
        pqrow[30] = 0.f; pqrow[31] = 0.f;
        for (int n = 0; n < 32; ++n) {
            ws[OFF_PQ + (size_t)tid*32 + n] = pqrow[n];
            bf16_t h = (bf16_t)pqrow[n];
            float hf = (float)h;
            pqh[n*64 + tid] = bf16bits(pqrow[n]);
            pql[n*64 + tid] = bf16bits(pqrow[n] - hf);
        }
    }
    __syncthreads();

    if (tid < 30) {
        double a20 = 0.0, a21 = 0.0;
        for (int p = 0; p < 64; ++p) {
            double pq = (double)ws[OFF_PQ + (size_t)p*32 + tid];
            a20 += (double)DPhi[0][p] * pq;
            a21 += (double)DPhi[1][p] * pq;
        }
        ws[OFF_M2 + 0*32 + tid] = (float)((double)inv0s[0]*a20 + (double)inv0s[1]*a21);
        ws[OFF_M2 + 1*32 + tid] = (float)((double)inv0s[2]*a20 + (double)inv0s[3]*a21);
    }

    if (tid < 64) {
        ushort_t* phh = (ushort_t*)(ws + OFF_PHIH);
        ushort_t* phl = (ushort_t*)(ws + OFF_PHIL);
        for (int n = 0; n < 32; ++n) {
            float f = Phi[n][tid];
            ws[OFF_PHIT + (size_t)tid*32 + n] = f;
            ushort_t hb = bf16bits(f);
            phh[tid*32 + n] = hb;
            phl[tid*32 + n] = bf16bits(f - bf16val(hb));
        }
        ws[OFF_TCHEB + tid] = tcs[tid];
    }

    if (tid < TEV) {
        float te = t_eval[tid];
        out[OUT_TEVAL + tid] = te;
        float tt = -1.f + 2.f*(te - t0)/(t1 - t0);
        float q0 = 1.f, q1 = tt;
        ws[OFF_PHIOUT + (size_t)tid*32 + 0] = q0;
        ws[OFF_PHIOUT + (size_t)tid*32 + 1] = q1;
        for (int k = 2; k < 32; ++k) { float qk = 2.f*tt*q1 - q0; ws[OFF_PHIOUT + (size_t)tid*32 + k] = qk; q0 = q1; q1 = qk; }
    }

    if (tid == 0) {
        double* acc = (double*)(ws + OFF_SCAL);
        acc[0] = 0.0;
        int* ip = (int*)(ws + OFF_SCAL + 2);
        ip[0] = 0;  // done
        ip[1] = 0;  // counter
    }
}

// ============ B_init [b][d][n] -> Bt [b][n][d] ============
__global__ __launch_bounds__(256) void transB_kernel(const float* __restrict__ Bin, float* __restrict__ Bt)
{
    const int t = threadIdx.x, b = blockIdx.x;
    const float* src = Bin + ((size_t)(b*NDIM + t)) * NTAIL;
    #pragma unroll
    for (int n = 0; n < NTAIL; ++n)
        Bt[((size_t)b*NTAIL + n)*NDIM + t] = src[n];
}

// ============ W [R][C] f32 -> Wt [C][R] bf16 ============
__global__ __launch_bounds__(256) void transW_kernel(const float* __restrict__ W, bf16_t* __restrict__ Wt,
                                                     int R, int C)
{
    __shared__ float Ls[64][65];
    const int r0 = blockIdx.x*64, c0 = blockIdx.y*64;
    const int lr = threadIdx.x >> 6, lc = threadIdx.x & 63;
    #pragma unroll
    for (int i = 0; i < 16; ++i) {
        int rr = i*4 + lr;
        Ls[rr][lc] = W[(size_t)(r0+rr)*C + c0+lc];
    }
    __syncthreads();
    #pragma unroll
    for (int i = 0; i < 16; ++i) {
        int cc = i*4 + lr;
        Wt[(size_t)(c0+cc)*R + r0 + lc] = (bf16_t)Ls[lc][cc];
    }
}

// ============ f_init ============
__global__ __launch_bounds__(512) void finit_h_kernel(const float* __restrict__ y, const float* __restrict__ W1,
                                                      const float* __restrict__ b1, const float* __restrict__ t_eval,
                                                      float* __restrict__ h1)
{
    __shared__ float ys[NDIM];
    const int t = threadIdx.x, b = blockIdx.x;
    if (t < NDIM) ys[t] = y[(size_t)b*NDIM + t];
    __syncthreads();
    float acc = b1[t] + t_eval[0];
    for (int d = 0; d < NDIM; ++d) acc += ys[d] * W1[(size_t)d*NHID + t];
    h1[(size_t)b*NHID + t] = tanhf(acc);
}

__global__ __launch_bounds__(256) void finit_rest_kernel(const float* __restrict__ y, const float* __restrict__ W2,
                                                         const float* __restrict__ b2, const float* __restrict__ h1,
                                                         const float* __restrict__ inv0, const float* __restrict__ M2,
                                                         float* __restrict__ yf2i, float* __restrict__ yM2)
{
    __shared__ float hs[NHID];
    const int t = threadIdx.x, b = blockIdx.x;
    hs[t] = h1[(size_t)b*NHID + t];
    hs[t+256] = h1[(size_t)b*NHID + 256 + t];
    __syncthreads();
    float f = b2[t];
    for (int h = 0; h < NHID; ++h) f += hs[h] * W2[(size_t)h*NDIM + t];
    const float yv = y[(size_t)b*NDIM + t];
    yf2i[((size_t)b*2 + 0)*NDIM + t] = yv*inv0[0] + f*inv0[2];
    yf2i[((size_t)b*2 + 1)*NDIM + t] = yv*inv0[1] + f*inv0[3];
    #pragma unroll
    for (int n = 0; n < NTAIL; ++n)
        yM2[((size_t)b*NTAIL + n)*NDIM + t] = yv*M2[n] + f*M2[32 + n];
}

// ============ fused iteration kernel: 512 blocks (1 batch each) x 256 threads, 2 blocks/CU ============
__global__ __launch_bounds__(256, 2) void iter_kernel(
    const float* __restrict__ pd2i, const float* __restrict__ yf2i, const float* __restrict__ tch,
    const bf16_t* __restrict__ W1t, const bf16_t* __restrict__ W2t,
    const float* __restrict__ b1f, const float* __restrict__ b2f,
    const ushort_t* __restrict__ PQhi, const ushort_t* __restrict__ PQlo,
    const ushort_t* __restrict__ phiH, const ushort_t* __restrict__ phiL,
    const float* __restrict__ yM2, float* __restrict__ Bt,
    double* __restrict__ accum, int* __restrict__ counter,
    int* __restrict__ done, float* __restrict__ outDelta)
{
    if (*done) return;
    __shared__ float pd2s[32][2];
    __shared__ float tchS[64];
    __shared__ double redd[4];
    __shared__ __align__(16) char smemA[33792];  // BfT hi/lo -> Ay [64][264]us -> FsT [256][33]u32
    __shared__ __align__(16) char smemB[17408];  // Hc [64][136]us
    __shared__ __align__(16) ushort_t PQHs[32*72];
    __shared__ __align__(16) ushort_t PQLs[32*72];

    const int t = threadIdx.x;
    const int b = blockIdx.x;            // batch index 0..511
    const int lane = t & 63, w = t >> 6;
    const int fr = lane & 15, quad = lane >> 4;

    // ---- constants into LDS ----
    if (t < 60) ((float*)pd2s)[t] = pd2i[t];
    if (t >= 64 && t < 128) tchS[t-64] = tch[t-64];
    {
        int e = t * 8;
        int r = e >> 6, c = e & 63;
        uint4 vh = *(const uint4*)(PQhi + e);
        uint4 vl = *(const uint4*)(PQlo + e);
        *(uint4*)(PQHs + r*72 + c) = vh;
        *(uint4*)(PQLs + r*72 + c) = vl;
    }
    __syncthreads();   // pd2s visible to all threads (round-7 had a latent race here)

    // ---- stage 0a: head coefficients per thread (t = d), write BfT hi/lo [256 d][32 n] swizzled ----
    {
        float cf[32];
        #pragma unroll
        for (int n = 0; n < NTAIL; ++n) cf[2+n] = Bt[((size_t)b*NTAIL + n)*NDIM + t];
        float c0 = yf2i[((size_t)b*2 + 0)*NDIM + t];
        float c1 = yf2i[((size_t)b*2 + 1)*NDIM + t];
        #pragma unroll
        for (int n = 0; n < NTAIL; ++n) { c0 -= cf[2+n]*pd2s[n][0]; c1 -= cf[2+n]*pd2s[n][1]; }
        cf[0] = c0; cf[1] = c1;
        unsigned* BH32 = (unsigned*)smemA;             // [256][16] u32 (block-swizzled)
        unsigned* BL32 = (unsigned*)(smemA + 16384);
        #pragma unroll
        for (int n2 = 0; n2 < 16; ++n2) {
            float f0 = cf[2*n2], f1 = cf[2*n2+1];
            ushort_t h0 = bf16bits(f0), h1 = bf16bits(f1);
            ushort_t l0 = bf16bits(f0 - bf16val(h0)), l1 = bf16bits(f1 - bf16val(h1));
            int idx = t*16 + ((n2 >> 2) ^ (t & 3))*4 + (n2 & 3);
            BH32[idx] = (unsigned)h0 | ((unsigned)h1 << 16);
            BL32[idx] = (unsigned)l0 | ((unsigned)l1 << 16);
        }
    }
    __syncthreads();

    // ---- stage 0b: y = Phi @ Bfull via MFMA (hi/lo 3-product), write Ay [64 p][264] bf16 ----
    ushort_t* Ay = (ushort_t*)smemA;
    {
        bf16x8 bH[4], bL[4];
        const ushort_t* BHu = (const ushort_t*)smemA;
        const ushort_t* BLu = (const ushort_t*)(smemA + 16384);
        #pragma unroll
        for (int j = 0; j < 4; ++j) {
            const int d = w*64 + j*16 + fr;
            const int off = d*32 + (quad ^ (d & 3))*8;
            bH[j] = *(const bf16x8*)(BHu + off);
            bL[j] = *(const bf16x8*)(BLu + off);
        }
        bf16x8 aH[4], aL[4];
        #pragma unroll
        for (int i = 0; i < 4; ++i) {
            aH[i] = *(const bf16x8*)(phiH + (i*16 + fr)*32 + quad*8);
            aL[i] = *(const bf16x8*)(phiL + (i*16 + fr)*32 + quad*8);
        }
        __syncthreads();   // all BfT reads done before Ay overwrite
        f32x4 accY[4][4];
        #pragma unroll
        for (int i = 0; i < 4; ++i)
            #pragma unroll
            for (int j = 0; j < 4; ++j) {
                f32x4 a = (f32x4){0.f,0.f,0.f,0.f};
                a = __builtin_amdgcn_mfma_f32_16x16x32_bf16(aH[i], bH[j], a, 0, 0, 0);
                a = __builtin_amdgcn_mfma_f32_16x16x32_bf16(aH[i], bL[j], a, 0, 0, 0);
                a = __builtin_amdgcn_mfma_f32_16x16x32_bf16(aL[i], bH[j], a, 0, 0, 0);
                accY[i][j] = a;
            }
        #pragma unroll
        for (int i = 0; i < 4; ++i)
            #pragma unroll
            for (int j = 0; j < 4; ++j)
                #pragma unroll
                for (int r = 0; r < 4; ++r) {
                    const int p = i*16 + quad*4 + r;
                    const int d = w*64 + j*16 + fr;
                    Ay[p*264 + d] = bf16bits(accY[i][j][r]);
                }
    }
    __syncthreads();

    // ---- GEMM1 + tanh + GEMM2 over 4 nh-passes of 128; W2 frags register-prefetched per pass ----
    ushort_t* Hc = (ushort_t*)smemB;     // [64][136]
    f32x4 accF[4][4];                    // rows i*16, d-cols w*64 + j*16
    #pragma unroll
    for (int i = 0; i < 4; ++i)
        #pragma unroll
        for (int j = 0; j < 4; ++j) accF[i][j] = (f32x4){0.f,0.f,0.f,0.f};

    #pragma unroll
    for (int pass = 0; pass < 4; ++pass) {
        // prefetch ALL W2 fragments for this pass; they land during GEMM1's MFMA burst
        bf16x8 w2f[4][4];   // [kt/32][j]
        #pragma unroll
        for (int kt4 = 0; kt4 < 4; ++kt4)
            #pragma unroll
            for (int j = 0; j < 4; ++j) {
                const int d = w*64 + j*16 + fr;
                w2f[kt4][j] = *(const bf16x8*)(W2t + (size_t)d*NHID + pass*128 + kt4*32 + quad*8);
            }
        // GEMM1: acc1 = y(64x256) @ W1 chunk (256 x 128)
        f32x4 acc1[4][2];
        #pragma unroll
        for (int i = 0; i < 4; ++i)
            #pragma unroll
            for (int j = 0; j < 2; ++j) acc1[i][j] = (f32x4){0.f,0.f,0.f,0.f};
        #pragma unroll
        for (int kt = 0; kt < NDIM; kt += 32) {
            bf16x8 af[4], bfj[2];
            #pragma unroll
            for (int i = 0; i < 4; ++i)
                af[i] = *(const bf16x8*)(Ay + (i*16 + fr)*264 + kt + quad*8);
            #pragma unroll
            for (int j = 0; j < 2; ++j) {
                const int ncol = pass*128 + w*32 + j*16 + fr;
                bfj[j] = *(const bf16x8*)(W1t + (size_t)ncol*NDIM + kt + quad*8);
            }
            #pragma unroll
            for (int i = 0; i < 4; ++i)
                #pragma unroll
                for (int j = 0; j < 2; ++j)
                    acc1[i][j] = __builtin_amdgcn_mfma_f32_16x16x32_bf16(af[i], bfj[j], acc1[i][j], 0, 0, 0);
        }
        __syncthreads();   // prev pass GEMM2 Hc reads done (also drains w2f loads)
        #pragma unroll
        for (int i = 0; i < 4; ++i)
            #pragma unroll
            for (int j = 0; j < 2; ++j) {
                const int col = w*32 + j*16 + fr;
                const float bv = b1f[pass*128 + col];
                #pragma unroll
                for (int r = 0; r < 4; ++r) {
                    const int row = i*16 + quad*4 + r;   // = p, 0..63
                    float v = acc1[i][j][r] + bv + tchS[row];
                    v = fminf(fmaxf(v, -15.f), 15.f);
                    float e = __expf(2.f*v);
                    Hc[row*136 + col] = bf16bits((e - 1.f)/(e + 1.f));
                }
            }
        __syncthreads();
        // GEMM2 partial: accF += Hc(64x128) @ W2 chunk (128 x 256) — no global loads here
        #pragma unroll
        for (int kt4 = 0; kt4 < 4; ++kt4) {
            bf16x8 af[4];
            #pragma unroll
            for (int i = 0; i < 4; ++i)
                af[i] = *(const bf16x8*)(Hc + (i*16 + fr)*136 + kt4*32 + quad*8);
            #pragma unroll
            for (int i = 0; i < 4; ++i)
                #pragma unroll
                for (int j = 0; j < 4; ++j)
                    accF[i][j] = __builtin_amdgcn_mfma_f32_16x16x32_bf16(af[i], w2f[kt4][j], accF[i][j], 0, 0, 0);
        }
    }
    __syncthreads();   // last GEMM1's Ay reads done; smemA reusable

    // ---- F (+b2) -> FsT [256 d][33] u32 (bf16 row-pairs) ----
    {
        unsigned* FsT32 = (unsigned*)smemA;
        #pragma unroll
        for (int i = 0; i < 4; ++i)
            #pragma unroll
            for (int j = 0; j < 4; ++j) {
                const int d = w*64 + j*16 + fr;
                const float bv = b2f[d];
                #pragma unroll
                for (int rp = 0; rp < 2; ++rp) {
                    unsigned u0 = bf16bits(accF[i][j][rp*2]   + bv);
                    unsigned u1 = bf16bits(accF[i][j][rp*2+1] + bv);
                    FsT32[d*33 + i*8 + quad*2 + rp] = u0 | (u1 << 16);
                }
            }
    }
    __syncthreads();

    // ---- PQ contraction: B_new[n][d] = sum_p PQ[n][p]*F[p][d] - yM2, update Bt + norm ----
    double ss = 0.0;
    {
        const ushort_t* FsTu = (const ushort_t*)smemA;
        f32x4 acc2[2][4];
        #pragma unroll
        for (int m2 = 0; m2 < 2; ++m2)
            #pragma unroll
            for (int j2 = 0; j2 < 4; ++j2) acc2[m2][j2] = (f32x4){0.f,0.f,0.f,0.f};
        #pragma unroll
        for (int kk = 0; kk < 2; ++kk) {
            bf16x8 ah[2], al[2];
            #pragma unroll
            for (int m2 = 0; m2 < 2; ++m2) {
                const int off = (m2*16 + fr)*72 + kk*32 + quad*8;
                ah[m2] = *(const bf16x8*)(PQHs + off);
                al[m2] = *(const bf16x8*)(PQLs + off);
            }
            #pragma unroll
            for (int j2 = 0; j2 < 4; ++j2) {
                const int d2 = w*64 + j2*16 + fr;
                bf16x8 bfv = *(const bf16x8*)(FsTu + d2*66 + kk*32 + quad*8);
                #pragma unroll
                for (int m2 = 0; m2 < 2; ++m2) {
                    acc2[m2][j2] = __builtin_amdgcn_mfma_f32_16x16x32_bf16(ah[m2], bfv, acc2[m2][j2], 0, 0, 0);
                    acc2[m2][j2] = __builtin_amdgcn_mfma_f32_16x16x32_bf16(al[m2], bfv, acc2[m2][j2], 0, 0, 0);
                }
            }
        }
        #pragma unroll
        for (int m2 = 0; m2 < 2; ++m2)
            #pragma unroll
            for (int j2 = 0; j2 < 4; ++j2)
                #pragma unroll
                for (int rr = 0; rr < 4; ++rr) {
                    const int n = m2*16 + quad*4 + rr;
                    if (n < NTAIL) {
                        const int d = w*64 + j2*16 + fr;
                        const size_t idx = ((size_t)b*NTAIL + n)*NDIM + d;
                        float val = acc2[m2][j2][rr] - yM2[idx];
                        float old = Bt[idx];
                        float diff = val - old;
                        Bt[idx] = val;
                        ss += (double)diff*(double)diff;
                    }
                }
    }

    #pragma unroll
    for (int off = 32; off > 0; off >>= 1) ss += __shfl_down(ss, off, 64);
    if (lane == 0) redd[w] = ss;
    __syncthreads();
    if (t == 0) {
        double tot = redd[0] + redd[1] + redd[2] + redd[3];
        atomicAdd(accum, tot);
        __threadfence();
        int old = atomicAdd(counter, 1);
        if (old == 511) {   // last of 512 blocks
            unsigned long long raw = atomicExch((unsigned long long*)accum, 0ull);
            double total; __builtin_memcpy(&total, &raw, 8);
            float dl = (float)sqrt(total);
            *outDelta = dl;
            *counter = 0;
            if (dl < TOLF) *done = 1;
        }
    }
}

// ============ epilogue: traj + B output ============
__global__ __launch_bounds__(256) void kernelEpi(const float* __restrict__ PhiOut, const float* __restrict__ pd2i,
                                                 const float* __restrict__ yf2i, const float* __restrict__ Bt,
                                                 float* __restrict__ outTraj, float* __restrict__ outB)
{
    __shared__ float Po[16][32];
    const int t = threadIdx.x, b = blockIdx.x;
    for (int i = t; i < 512; i += 256) ((float*)Po)[i] = PhiOut[i];
    __syncthreads();
    float cf[32];
    #pragma unroll
    for (int n = 0; n < NTAIL; ++n) cf[2+n] = Bt[((size_t)b*NTAIL + n)*NDIM + t];
    float c0 = yf2i[((size_t)b*2 + 0)*NDIM + t];
    float c1 = yf2i[((size_t)b*2 + 1)*NDIM + t];
    #pragma unroll
    for (int n = 0; n < NTAIL; ++n) { c0 -= cf[2+n]*pd2i[n*2]; c1 -= cf[2+n]*pd2i[n*2+1]; }
    cf[0] = c0; cf[1] = c1;
    for (int tt = 0; tt < TEV; ++tt) {
        float s = 0.f;
        #pragma unroll
        for (int k = 0; k < 32; ++k) s += cf[k]*Po[tt][k];
        outTraj[((size_t)tt*NBATCH + b)*NDIM + t] = s;
    }
    float* ob = outB + ((size_t)(b*NDIM + t))*NTAIL;
    #pragma unroll
    for (int n = 0; n < NTAIL; ++n) ob[n] = cf[2+n];
}

extern "C" void kernel_launch(void* const* d_in, const int* in_sizes, int n_in,
                              void* d_out, int out_size, void* d_ws, size_t ws_size,
                              hipStream_t stream)
{
    const float* y_init = (const float*)d_in[0];
    const float* t_eval = (const float*)d_in[1];
    const float* B_init = (const float*)d_in[2];
    const float* W1     = (const float*)d_in[3];
    const float* b1     = (const float*)d_in[4];
    const float* W2     = (const float*)d_in[5];
    const float* b2     = (const float*)d_in[6];
    float* out = (float*)d_out;
    float* ws  = (float*)d_ws;
    if (ws_size < WS_FLOATS * sizeof(float)) return;

    float* tcheb = ws + OFF_TCHEB;
    float* pd2i  = ws + OFF_PD2I;
    float* M2    = ws + OFF_M2;
    float* inv0  = ws + OFF_INV0;
    float* PhiOut= ws + OFF_PHIOUT;
    double* accum = (double*)(ws + OFF_SCAL);
    int* done    = (int*)(ws + OFF_SCAL + 2);
    int* counter = (int*)(ws + OFF_SCAL + 3);
    float* h1   = ws + OFF_H1F;
    float* yf2i = ws + OFF_YF2I;
    float* yM2  = ws + OFF_YM2;
    float* Bt   = ws + OFF_BT;
    bf16_t* W1t = (bf16_t*)(ws + OFF_W1T);
    bf16_t* W2t = (bf16_t*)(ws + OFF_W2T);
    ushort_t* pqh = (ushort_t*)(ws + OFF_PQBH);
    ushort_t* pql = (ushort_t*)(ws + OFF_PQBL);
    ushort_t* phh = (ushort_t*)(ws + OFF_PHIH);
    ushort_t* phl = (ushort_t*)(ws + OFF_PHIL);

    setup_kernel<<<1, 256, 0, stream>>>(t_eval, ws, out);
    transB_kernel<<<NBATCH, 256, 0, stream>>>(B_init, Bt);
    transW_kernel<<<dim3(NDIM/64, NHID/64), 256, 0, stream>>>(W1, W1t, NDIM, NHID);
    transW_kernel<<<dim3(NHID/64, NDIM/64), 256, 0, stream>>>(W2, W2t, NHID, NDIM);
    finit_h_kernel<<<NBATCH, 512, 0, stream>>>(y_init, W1, b1, t_eval, h1);
    finit_rest_kernel<<<NBATCH, 256, 0, stream>>>(y_init, W2, b2, h1, inv0, M2, yf2i, yM2);

    for (int it = 0; it < MAXIT; ++it) {
        iter_kernel<<<NBATCH, 256, 0, stream>>>(pd2i, yf2i, tcheb, W1t, W2t, b1, b2,
                                                pqh, pql, phh, phl, yM2, Bt,
                                                accum, counter, done, out + OUT_DELTA);
    }
    kernelEpi<<<NBATCH, 256, 0, stream>>>(PhiOut, pd2i, yf2i, Bt, out + OUT_TRAJ, out + OUT_B);
}